// Round 2
// baseline (311.037 us; speedup 1.0000x reference)
//
#include <hip/hip_runtime.h>
#include <hip/hip_cooperative_groups.h>

namespace cg = cooperative_groups;

// SmoothingModule: s[t] = q[t]*s[t-1] + pe[t]*z[t] (per b,d), out masked by t < lengths[b].
// Fused cooperative kernel: CHUNK=16 rows/block-chunk, z tile held in registers across
// two grid.sync()s so z is read from HBM exactly once.
//  Phase 1: local scan -> S[b,c,:], A[b,c]. Masked chunks (t0>=L) write out zeros here.
//  Phase 2: blocks 0..B*D4-1: Hillis-Steele scan of affine maps over chunk axis -> Carry.
//  Phase 3: s = Carry; replay scan from registers; mask + coalesced store.
// Fallback: 3-kernel path (verified in prior rounds) if cooperative launch unavailable.

#define CHUNK 16
#define NCMAX 512  // fallback path supports T up to 8192

__global__ __launch_bounds__(128, 2) void k_fused(
    const float* __restrict__ z, const float* __restrict__ P,
    const int* __restrict__ lengths,
    float* __restrict__ S, float* __restrict__ A, float* __restrict__ Carry,
    float* __restrict__ out, int B, int T, int D4, int NC) {
  cg::grid_group grid = cg::this_grid();
  const int blk = blockIdx.x;
  const int b = blk / NC, c = blk % NC;
  const int t0 = c * CHUNK;
  const int tid = threadIdx.x;
  const int L = lengths[b];
  const int nt = min(CHUNK, T - t0);
  const bool masked = (t0 >= L);

  __shared__ float p_s[CHUNK], q_s[CHUNK];
  __shared__ float sh_a[128];
  __shared__ float4 sh_s[128];

  const float4 zero = make_float4(0.f, 0.f, 0.f, 0.f);
  float4 zreg[CHUNK];
  const float4* z4 = (const float4*)z;
  float4* o4 = (float4*)out;
  const size_t zbase = ((size_t)b * T + t0) * D4;

  if (tid < CHUNK) {
    int tg = t0 + tid;
    float p = (tg < T && !masked) ? P[(size_t)b * T + tg] : 0.0f;
    p = fminf(fmaxf(p, 0.0f), 1.0f - 1e-6f);
    q_s[tid] = 1.0f - p;
    p_s[tid] = fmaxf(p, 1e-6f);
  }
  __syncthreads();

  // ---- Phase 1: chunk-local scan (z tile -> registers) ----
  float4 s = zero;
  if (tid < D4) {
    if (!masked) {
#pragma unroll
      for (int t = 0; t < CHUNK; ++t)
        if (t < nt) zreg[t] = z4[zbase + (size_t)t * D4 + tid];
#pragma unroll
      for (int t = 0; t < CHUNK; ++t)
        if (t < nt) {
          float q = q_s[t], pe = p_s[t];
          s.x = fmaf(q, s.x, pe * zreg[t].x);
          s.y = fmaf(q, s.y, pe * zreg[t].y);
          s.z = fmaf(q, s.z, pe * zreg[t].z);
          s.w = fmaf(q, s.w, pe * zreg[t].w);
        }
    } else {
      // fully-masked chunk: write output zeros now (overlaps live blocks' loads)
      for (int t = 0; t < nt; ++t) o4[zbase + (size_t)t * D4 + tid] = zero;
    }
    ((float4*)S)[((size_t)b * NC + c) * D4 + tid] = s;  // zero when masked
  }
  if (tid == 0) {
    float a = 1.0f;
    if (!masked)
      for (int t = 0; t < nt; ++t) a *= q_s[t];
    A[b * NC + c] = a;  // identity map when masked
  }

  grid.sync();

  // ---- Phase 2: scan affine maps (a, S) over chunk axis; blocks 0..B*D4-1 ----
  {
    const int ntask = B * D4;
    if (blk < ntask) {
      const int tb = blk / D4, td4 = blk % D4;
      const int half = NC >> 1;
      float a0 = 1.f, pa = 1.f;
      float4 s0 = zero, ps = zero;
      if (tid < half) {
        int c0 = 2 * tid, c1 = c0 + 1;
        a0 = A[tb * NC + c0];
        float a1 = A[tb * NC + c1];
        s0 = ((const float4*)S)[((size_t)tb * NC + c0) * D4 + td4];
        float4 s1 = ((const float4*)S)[((size_t)tb * NC + c1) * D4 + td4];
        pa = a1 * a0;
        ps.x = fmaf(a1, s0.x, s1.x);
        ps.y = fmaf(a1, s0.y, s1.y);
        ps.z = fmaf(a1, s0.z, s1.z);
        ps.w = fmaf(a1, s0.w, s1.w);
        sh_a[tid] = pa;
        sh_s[tid] = ps;
      }
      __syncthreads();
      for (int off = 1; off < half; off <<= 1) {
        float Ap = 1.f;
        float4 Sp = zero;
        bool has = (tid >= off) && (tid < half);
        if (has) { Ap = sh_a[tid - off]; Sp = sh_s[tid - off]; }
        __syncthreads();
        if (has) {
          ps.x = fmaf(pa, Sp.x, ps.x);
          ps.y = fmaf(pa, Sp.y, ps.y);
          ps.z = fmaf(pa, Sp.z, ps.z);
          ps.w = fmaf(pa, Sp.w, ps.w);
          pa *= Ap;
          sh_a[tid] = pa;
          sh_s[tid] = ps;
        }
        __syncthreads();
      }
      if (tid < half) {
        float4 Pp = (tid > 0) ? sh_s[tid - 1] : zero;  // composite through chunk 2*tid-1
        float4* C4 = (float4*)Carry;
        size_t base = ((size_t)tb * D4 + td4) * NC;
        C4[base + 2 * tid] = Pp;
        float4 c1v;
        c1v.x = fmaf(a0, Pp.x, s0.x);
        c1v.y = fmaf(a0, Pp.y, s0.y);
        c1v.z = fmaf(a0, Pp.z, s0.z);
        c1v.w = fmaf(a0, Pp.w, s0.w);
        C4[base + 2 * tid + 1] = c1v;
      }
    }
  }

  grid.sync();

  // ---- Phase 3: replay scan from registers with carry-in; mask + store ----
  if (!masked && tid < D4) {
    float4 sc = ((const float4*)Carry)[((size_t)b * D4 + tid) * NC + c];
#pragma unroll
    for (int t = 0; t < CHUNK; ++t)
      if (t < nt) {
        float q = q_s[t], pe = p_s[t];
        sc.x = fmaf(q, sc.x, pe * zreg[t].x);
        sc.y = fmaf(q, sc.y, pe * zreg[t].y);
        sc.z = fmaf(q, sc.z, pe * zreg[t].z);
        sc.w = fmaf(q, sc.w, pe * zreg[t].w);
        float4 o = ((t0 + t) < L) ? sc : zero;
        o4[zbase + (size_t)t * D4 + tid] = o;
      }
  }
}

// ---------------- fallback 3-kernel path (verified) ----------------

__global__ __launch_bounds__(128) void k_local(
    const float* __restrict__ z, const float* __restrict__ P,
    const int* __restrict__ lengths,
    float* __restrict__ S, float* __restrict__ A,
    int B, int T, int D, int NC) {
  int blk = blockIdx.x;
  int b = blk / NC, c = blk % NC;
  int t0 = c * CHUNK;
  int tid = threadIdx.x;
  int D4 = D >> 2;
  float4* S4 = (float4*)(S + ((size_t)b * NC + c) * D);
  int L = lengths[b];
  if (t0 >= L) {
    float4 zero = make_float4(0.f, 0.f, 0.f, 0.f);
    for (int d4 = tid; d4 < D4; d4 += blockDim.x) S4[d4] = zero;
    if (tid == 0) A[b * NC + c] = 1.0f;
    return;
  }
  __shared__ float p_s[CHUNK], q_s[CHUNK];
  if (tid < CHUNK) {
    int tg = t0 + tid;
    float p = (tg < T) ? P[(size_t)b * T + tg] : 0.0f;
    p = fminf(fmaxf(p, 0.0f), 1.0f - 1e-6f);
    q_s[tid] = 1.0f - p;
    p_s[tid] = fmaxf(p, 1e-6f);
  }
  __syncthreads();
  int nt = min(CHUNK, T - t0);
  const float4* z4 = (const float4*)(z + ((size_t)b * T + t0) * D);
  for (int d4 = tid; d4 < D4; d4 += blockDim.x) {
    float4 s = make_float4(0.f, 0.f, 0.f, 0.f);
#pragma unroll
    for (int t = 0; t < CHUNK; ++t) {
      if (t < nt) {
        float4 zv = z4[(size_t)t * D4 + d4];
        float q = q_s[t], pe = p_s[t];
        s.x = fmaf(q, s.x, pe * zv.x);
        s.y = fmaf(q, s.y, pe * zv.y);
        s.z = fmaf(q, s.z, pe * zv.z);
        s.w = fmaf(q, s.w, pe * zv.w);
      }
    }
    S4[d4] = s;
  }
  if (tid == 0) {
    float r = 1.0f;
    for (int t = 0; t < nt; ++t) r *= q_s[t];
    A[b * NC + c] = r;
  }
}

__global__ void k_carry(
    const float* __restrict__ S, const float* __restrict__ A,
    float* __restrict__ Carry, int D4, int NC) {
  int b = blockIdx.x / D4;
  int d4 = blockIdx.x % D4;
  int c = threadIdx.x;
  __shared__ float sh_a[NCMAX];
  __shared__ float4 sh_v[NCMAX];
  float a = A[b * NC + c];
  const float4* S4 = (const float4*)S;
  float4 sv = S4[((size_t)b * NC + c) * D4 + d4];
  sh_a[c] = a;
  sh_v[c] = sv;
  __syncthreads();
  for (int off = 1; off < NC; off <<= 1) {
    float ap = 1.0f;
    float4 vp = make_float4(0.f, 0.f, 0.f, 0.f);
    bool has = (c >= off);
    if (has) { ap = sh_a[c - off]; vp = sh_v[c - off]; }
    __syncthreads();
    if (has) {
      sv.x = fmaf(a, vp.x, sv.x);
      sv.y = fmaf(a, vp.y, sv.y);
      sv.z = fmaf(a, vp.z, sv.z);
      sv.w = fmaf(a, vp.w, sv.w);
      a *= ap;
      sh_a[c] = a;
      sh_v[c] = sv;
    }
    __syncthreads();
  }
  float4 car = make_float4(0.f, 0.f, 0.f, 0.f);
  if (c > 0) car = sh_v[c - 1];
  float4* C4 = (float4*)Carry;
  C4[((size_t)b * NC + c) * D4 + d4] = car;
}

__global__ __launch_bounds__(128) void k_apply(
    const float* __restrict__ z, const float* __restrict__ P,
    const float* __restrict__ Carry, const int* __restrict__ lengths,
    float* __restrict__ out,
    int B, int T, int D, int NC) {
  int blk = blockIdx.x;
  int b = blk / NC, c = blk % NC;
  int t0 = c * CHUNK;
  int tid = threadIdx.x;
  int D4 = D >> 2;
  int nt = min(CHUNK, T - t0);
  float4* o4 = (float4*)(out + ((size_t)b * T + t0) * D);
  int L = lengths[b];
  if (t0 >= L) {
    float4 zero = make_float4(0.f, 0.f, 0.f, 0.f);
    for (int t = 0; t < nt; ++t)
      for (int d4 = tid; d4 < D4; d4 += blockDim.x)
        o4[(size_t)t * D4 + d4] = zero;
    return;
  }
  __shared__ float p_s[CHUNK], q_s[CHUNK];
  if (tid < CHUNK) {
    int tg = t0 + tid;
    float p = (tg < T) ? P[(size_t)b * T + tg] : 0.0f;
    p = fminf(fmaxf(p, 0.0f), 1.0f - 1e-6f);
    q_s[tid] = 1.0f - p;
    p_s[tid] = fmaxf(p, 1e-6f);
  }
  __syncthreads();
  const float4* z4 = (const float4*)(z + ((size_t)b * T + t0) * D);
  const float4* C4 = (const float4*)(Carry + ((size_t)b * NC + c) * D);
  for (int d4 = tid; d4 < D4; d4 += blockDim.x) {
    float4 s = C4[d4];
#pragma unroll
    for (int t = 0; t < CHUNK; ++t) {
      if (t < nt) {
        float4 zv = z4[(size_t)t * D4 + d4];
        float q = q_s[t], pe = p_s[t];
        s.x = fmaf(q, s.x, pe * zv.x);
        s.y = fmaf(q, s.y, pe * zv.y);
        s.z = fmaf(q, s.z, pe * zv.z);
        s.w = fmaf(q, s.w, pe * zv.w);
        float4 o = ((t0 + t) < L) ? s : make_float4(0.f, 0.f, 0.f, 0.f);
        o4[(size_t)t * D4 + d4] = o;
      }
    }
  }
}

extern "C" void kernel_launch(void* const* d_in, const int* in_sizes, int n_in,
                              void* d_out, int out_size, void* d_ws, size_t ws_size,
                              hipStream_t stream) {
  const float* z = (const float*)d_in[0];
  const float* P = (const float*)d_in[1];
  const int* lengths = (const int*)d_in[2];
  float* out = (float*)d_out;

  int B = in_sizes[2];
  int T = in_sizes[1] / B;
  int D = in_sizes[0] / in_sizes[1];
  int NC = (T + CHUNK - 1) / CHUNK;  // 256 for T=4096
  int D4 = D >> 2;                   // 128 for D=512

  // workspace: S [B*NC*D] | A [B*NC] (padded to 4) | Carry [B*NC*D]
  float* S = (float*)d_ws;
  float* A = S + (size_t)B * NC * D;
  float* Carry = A + (((size_t)B * NC + 3) & ~(size_t)3);

  // Fused cooperative path: requires D4<=128 (one float4/thread), even NC<=256
  // (phase-2 pair scan in one 128-thread block), grid<=1024 (co-residency at
  // >=4 blocks/CU guaranteed by launch_bounds VGPR cap).
  if ((D & 3) == 0 && D4 >= 64 && D4 <= 128 && NC >= 2 && NC <= 256 &&
      (NC & 1) == 0 && (size_t)B * NC <= 1024) {
    void* args[] = {(void*)&z, (void*)&P, (void*)&lengths, (void*)&S, (void*)&A,
                    (void*)&Carry, (void*)&out, (void*)&B, (void*)&T, (void*)&D4,
                    (void*)&NC};
    hipError_t e = hipLaunchCooperativeKernel((const void*)k_fused, dim3(B * NC),
                                              dim3(128), args, 0, stream);
    if (e == hipSuccess) return;
    (void)hipGetLastError();  // clear error, fall through to 3-kernel path
  }

  k_local<<<dim3(B * NC), dim3(128), 0, stream>>>(z, P, lengths, S, A, B, T, D, NC);
  k_carry<<<dim3(B * D4), dim3(NC), 0, stream>>>(S, A, Carry, D4, NC);
  k_apply<<<dim3(B * NC), dim3(128), 0, stream>>>(z, P, Carry, lengths, out, B, T, D, NC);
}

// Round 3
// 105.225 us; speedup vs baseline: 2.9559x; 2.9559x over previous
//
#include <hip/hip_runtime.h>

// SmoothingModule: s[t] = q[t]*s[t-1] + pe[t]*z[t] (per b,d), out masked by t < lengths[b].
// Two kernels, CHUNK=16 rows per block, no grid sync, no Carry buffer:
//  k_local: live chunks -> chunk-local scan end S[b,c,:] (float4) + A[b,c]=prod q.
//           fully-masked chunks (t0 >= lengths[b]) write output zeros here and skip z.
//           (Masked chunks' S/A are never consumed: any live chunk c only reads cp < c,
//            and cp < c_live implies chunk cp is fully live.)
//  k_apply: per live chunk c: LDS suffix-product scan of A (8 Hillis-Steele steps)
//           -> W[cp] = prod_{j=cp+1..c-1} A[j]; carry[d] = sum_{cp<c} W[cp]*S[cp][d]
//           (coalesced rows, S is 2 MB -> L2/L3 resident); then replay 16-row scan
//           from z and store with per-row length mask.
// Fast path requires D%4==0, D/4 <= 128, NC <= 256; otherwise verified 3-kernel fallback.

#define CHUNK 16
#define NCMAX 512  // fallback supports T up to 8192

__global__ __launch_bounds__(128) void k_local(
    const float* __restrict__ z, const float* __restrict__ P,
    const int* __restrict__ lengths,
    float* __restrict__ S, float* __restrict__ A,
    float* __restrict__ out, int B, int T, int D4, int NC) {
  const int blk = blockIdx.x;
  const int b = blk / NC, c = blk % NC;
  const int t0 = c * CHUNK;
  const int tid = threadIdx.x;
  const int L = lengths[b];
  const int nt = min(CHUNK, T - t0);
  const float4 zero = make_float4(0.f, 0.f, 0.f, 0.f);
  const size_t rowbase = ((size_t)b * T + t0) * D4;

  if (t0 >= L) {
    // fully-masked chunk: emit output zeros now; S/A never read.
    float4* o4 = (float4*)out;
    if (tid < D4)
      for (int t = 0; t < nt; ++t) o4[rowbase + (size_t)t * D4 + tid] = zero;
    return;
  }

  __shared__ float p_s[CHUNK], q_s[CHUNK];
  if (tid < CHUNK) {
    int tg = t0 + tid;
    float p = (tg < T) ? P[(size_t)b * T + tg] : 0.0f;
    p = fminf(fmaxf(p, 0.0f), 1.0f - 1e-6f);
    q_s[tid] = 1.0f - p;
    p_s[tid] = fmaxf(p, 1e-6f);
  }
  __syncthreads();

  if (tid < D4) {
    const float4* z4 = (const float4*)z;
    float4 zr[CHUNK];
#pragma unroll
    for (int t = 0; t < CHUNK; ++t)
      if (t < nt) zr[t] = z4[rowbase + (size_t)t * D4 + tid];
    float4 s = zero;
#pragma unroll
    for (int t = 0; t < CHUNK; ++t)
      if (t < nt) {
        float q = q_s[t], pe = p_s[t];
        s.x = fmaf(q, s.x, pe * zr[t].x);
        s.y = fmaf(q, s.y, pe * zr[t].y);
        s.z = fmaf(q, s.z, pe * zr[t].z);
        s.w = fmaf(q, s.w, pe * zr[t].w);
      }
    ((float4*)S)[((size_t)b * NC + c) * D4 + tid] = s;
  }
  if (tid == 0) {
    float r = 1.0f;
    for (int t = 0; t < nt; ++t) r *= q_s[t];
    A[b * NC + c] = r;
  }
}

__global__ __launch_bounds__(128) void k_apply(
    const float* __restrict__ z, const float* __restrict__ P,
    const float* __restrict__ S, const float* __restrict__ A,
    const int* __restrict__ lengths, float* __restrict__ out,
    int B, int T, int D4, int NC) {
  const int blk = blockIdx.x;
  const int b = blk / NC, c = blk % NC;
  const int t0 = c * CHUNK;
  const int tid = threadIdx.x;
  const int L = lengths[b];
  if (t0 >= L) return;  // k_local already wrote zeros
  const int nt = min(CHUNK, T - t0);
  const float4 zero = make_float4(0.f, 0.f, 0.f, 0.f);

  __shared__ float p_s[CHUNK], q_s[CHUNK];
  __shared__ float a_s[256];
  __shared__ float w_s[256];

  if (tid < CHUNK) {
    int tg = t0 + tid;
    float p = (tg < T) ? P[(size_t)b * T + tg] : 0.0f;
    p = fminf(fmaxf(p, 0.0f), 1.0f - 1e-6f);
    q_s[tid] = 1.0f - p;
    p_s[tid] = fmaxf(p, 1e-6f);
  }
  // A row into LDS (only entries < c are meaningful/used)
  for (int i = tid; i < NC; i += 128) a_s[i] = A[b * NC + i];
  __syncthreads();

  // suffix products: w_s[cp] = prod_{j=cp+1}^{c-1} a_s[j]  (=1 for cp >= c-1)
  {
    int i0 = tid, i1 = tid + 128;
    w_s[i0] = (i0 < c - 1) ? a_s[i0 + 1] : 1.0f;
    w_s[i1] = (i1 < c - 1) ? a_s[i1 + 1] : 1.0f;
    __syncthreads();
#pragma unroll
    for (int off = 1; off < 256; off <<= 1) {
      float v0 = (i0 + off < 256) ? w_s[i0 + off] : 1.0f;
      float v1 = (i1 + off < 256) ? w_s[i1 + off] : 1.0f;
      __syncthreads();
      w_s[i0] *= v0;
      w_s[i1] *= v1;
      __syncthreads();
    }
  }

  if (tid < D4) {
    // carry = sum_{cp<c} w_s[cp] * S[b,cp,:]; coalesced rows, L2/L3 resident
    const float4* S4 = (const float4*)S + (size_t)b * NC * D4 + tid;
    float4 a0 = zero, a1 = zero, a2 = zero, a3 = zero;
    int cp = 0;
    for (; cp + 4 <= c; cp += 4) {
      float w0 = w_s[cp], w1 = w_s[cp + 1], w2 = w_s[cp + 2], w3 = w_s[cp + 3];
      float4 r0 = S4[(size_t)cp * D4];
      float4 r1 = S4[(size_t)(cp + 1) * D4];
      float4 r2 = S4[(size_t)(cp + 2) * D4];
      float4 r3 = S4[(size_t)(cp + 3) * D4];
      a0.x = fmaf(w0, r0.x, a0.x); a0.y = fmaf(w0, r0.y, a0.y);
      a0.z = fmaf(w0, r0.z, a0.z); a0.w = fmaf(w0, r0.w, a0.w);
      a1.x = fmaf(w1, r1.x, a1.x); a1.y = fmaf(w1, r1.y, a1.y);
      a1.z = fmaf(w1, r1.z, a1.z); a1.w = fmaf(w1, r1.w, a1.w);
      a2.x = fmaf(w2, r2.x, a2.x); a2.y = fmaf(w2, r2.y, a2.y);
      a2.z = fmaf(w2, r2.z, a2.z); a2.w = fmaf(w2, r2.w, a2.w);
      a3.x = fmaf(w3, r3.x, a3.x); a3.y = fmaf(w3, r3.y, a3.y);
      a3.z = fmaf(w3, r3.z, a3.z); a3.w = fmaf(w3, r3.w, a3.w);
    }
    for (; cp < c; ++cp) {
      float w = w_s[cp];
      float4 r = S4[(size_t)cp * D4];
      a0.x = fmaf(w, r.x, a0.x); a0.y = fmaf(w, r.y, a0.y);
      a0.z = fmaf(w, r.z, a0.z); a0.w = fmaf(w, r.w, a0.w);
    }
    float4 s;
    s.x = (a0.x + a1.x) + (a2.x + a3.x);
    s.y = (a0.y + a1.y) + (a2.y + a3.y);
    s.z = (a0.z + a1.z) + (a2.z + a3.z);
    s.w = (a0.w + a1.w) + (a2.w + a3.w);

    const size_t rowbase = ((size_t)b * T + t0) * D4;
    const float4* z4 = (const float4*)z;
    float4* o4 = (float4*)out;
#pragma unroll
    for (int t = 0; t < CHUNK; ++t)
      if (t < nt) {
        float4 zv = z4[rowbase + (size_t)t * D4 + tid];
        float q = q_s[t], pe = p_s[t];
        s.x = fmaf(q, s.x, pe * zv.x);
        s.y = fmaf(q, s.y, pe * zv.y);
        s.z = fmaf(q, s.z, pe * zv.z);
        s.w = fmaf(q, s.w, pe * zv.w);
        float4 o = ((t0 + t) < L) ? s : zero;
        o4[rowbase + (size_t)t * D4 + tid] = o;
      }
  }
}

// ---------------- fallback 3-kernel path (verified round 1) ----------------

__global__ __launch_bounds__(128) void f_local(
    const float* __restrict__ z, const float* __restrict__ P,
    const int* __restrict__ lengths,
    float* __restrict__ S, float* __restrict__ A,
    int B, int T, int D, int NC) {
  int blk = blockIdx.x;
  int b = blk / NC, c = blk % NC;
  int t0 = c * CHUNK;
  int tid = threadIdx.x;
  int D4 = D >> 2;
  float4* S4 = (float4*)(S + ((size_t)b * NC + c) * D);
  int L = lengths[b];
  if (t0 >= L) {
    float4 zero = make_float4(0.f, 0.f, 0.f, 0.f);
    for (int d4 = tid; d4 < D4; d4 += blockDim.x) S4[d4] = zero;
    if (tid == 0) A[b * NC + c] = 1.0f;
    return;
  }
  __shared__ float p_s[CHUNK], q_s[CHUNK];
  if (tid < CHUNK) {
    int tg = t0 + tid;
    float p = (tg < T) ? P[(size_t)b * T + tg] : 0.0f;
    p = fminf(fmaxf(p, 0.0f), 1.0f - 1e-6f);
    q_s[tid] = 1.0f - p;
    p_s[tid] = fmaxf(p, 1e-6f);
  }
  __syncthreads();
  int nt = min(CHUNK, T - t0);
  const float4* z4 = (const float4*)(z + ((size_t)b * T + t0) * D);
  for (int d4 = tid; d4 < D4; d4 += blockDim.x) {
    float4 s = make_float4(0.f, 0.f, 0.f, 0.f);
#pragma unroll
    for (int t = 0; t < CHUNK; ++t) {
      if (t < nt) {
        float4 zv = z4[(size_t)t * D4 + d4];
        float q = q_s[t], pe = p_s[t];
        s.x = fmaf(q, s.x, pe * zv.x);
        s.y = fmaf(q, s.y, pe * zv.y);
        s.z = fmaf(q, s.z, pe * zv.z);
        s.w = fmaf(q, s.w, pe * zv.w);
      }
    }
    S4[d4] = s;
  }
  if (tid == 0) {
    float r = 1.0f;
    for (int t = 0; t < nt; ++t) r *= q_s[t];
    A[b * NC + c] = r;
  }
}

__global__ void f_carry(
    const float* __restrict__ S, const float* __restrict__ A,
    float* __restrict__ Carry, int D4, int NC) {
  int b = blockIdx.x / D4;
  int d4 = blockIdx.x % D4;
  int c = threadIdx.x;
  __shared__ float sh_a[NCMAX];
  __shared__ float4 sh_v[NCMAX];
  float a = A[b * NC + c];
  const float4* S4 = (const float4*)S;
  float4 sv = S4[((size_t)b * NC + c) * D4 + d4];
  sh_a[c] = a;
  sh_v[c] = sv;
  __syncthreads();
  for (int off = 1; off < NC; off <<= 1) {
    float ap = 1.0f;
    float4 vp = make_float4(0.f, 0.f, 0.f, 0.f);
    bool has = (c >= off);
    if (has) { ap = sh_a[c - off]; vp = sh_v[c - off]; }
    __syncthreads();
    if (has) {
      sv.x = fmaf(a, vp.x, sv.x);
      sv.y = fmaf(a, vp.y, sv.y);
      sv.z = fmaf(a, vp.z, sv.z);
      sv.w = fmaf(a, vp.w, sv.w);
      a *= ap;
      sh_a[c] = a;
      sh_v[c] = sv;
    }
    __syncthreads();
  }
  float4 car = make_float4(0.f, 0.f, 0.f, 0.f);
  if (c > 0) car = sh_v[c - 1];
  float4* C4 = (float4*)Carry;
  C4[((size_t)b * NC + c) * D4 + d4] = car;
}

__global__ __launch_bounds__(128) void f_apply(
    const float* __restrict__ z, const float* __restrict__ P,
    const float* __restrict__ Carry, const int* __restrict__ lengths,
    float* __restrict__ out,
    int B, int T, int D, int NC) {
  int blk = blockIdx.x;
  int b = blk / NC, c = blk % NC;
  int t0 = c * CHUNK;
  int tid = threadIdx.x;
  int D4 = D >> 2;
  int nt = min(CHUNK, T - t0);
  float4* o4 = (float4*)(out + ((size_t)b * T + t0) * D);
  int L = lengths[b];
  if (t0 >= L) {
    float4 zero = make_float4(0.f, 0.f, 0.f, 0.f);
    for (int t = 0; t < nt; ++t)
      for (int d4 = tid; d4 < D4; d4 += blockDim.x)
        o4[(size_t)t * D4 + d4] = zero;
    return;
  }
  __shared__ float p_s[CHUNK], q_s[CHUNK];
  if (tid < CHUNK) {
    int tg = t0 + tid;
    float p = (tg < T) ? P[(size_t)b * T + tg] : 0.0f;
    p = fminf(fmaxf(p, 0.0f), 1.0f - 1e-6f);
    q_s[tid] = 1.0f - p;
    p_s[tid] = fmaxf(p, 1e-6f);
  }
  __syncthreads();
  const float4* z4 = (const float4*)(z + ((size_t)b * T + t0) * D);
  const float4* C4 = (const float4*)(Carry + ((size_t)b * NC + c) * D);
  for (int d4 = tid; d4 < D4; d4 += blockDim.x) {
    float4 s = C4[d4];
#pragma unroll
    for (int t = 0; t < CHUNK; ++t) {
      if (t < nt) {
        float4 zv = z4[(size_t)t * D4 + d4];
        float q = q_s[t], pe = p_s[t];
        s.x = fmaf(q, s.x, pe * zv.x);
        s.y = fmaf(q, s.y, pe * zv.y);
        s.z = fmaf(q, s.z, pe * zv.z);
        s.w = fmaf(q, s.w, pe * zv.w);
        float4 o = ((t0 + t) < L) ? s : make_float4(0.f, 0.f, 0.f, 0.f);
        o4[(size_t)t * D4 + d4] = o;
      }
    }
  }
}

extern "C" void kernel_launch(void* const* d_in, const int* in_sizes, int n_in,
                              void* d_out, int out_size, void* d_ws, size_t ws_size,
                              hipStream_t stream) {
  const float* z = (const float*)d_in[0];
  const float* P = (const float*)d_in[1];
  const int* lengths = (const int*)d_in[2];
  float* out = (float*)d_out;

  int B = in_sizes[2];
  int T = in_sizes[1] / B;
  int D = in_sizes[0] / in_sizes[1];
  int NC = (T + CHUNK - 1) / CHUNK;  // 256 for T=4096
  int D4 = D >> 2;                   // 128 for D=512

  // workspace: S [B*NC*D] | A [B*NC] (padded) | Carry [B*NC*D] (fallback only)
  float* S = (float*)d_ws;
  float* A = S + (size_t)B * NC * D;
  float* Carry = A + (((size_t)B * NC + 3) & ~(size_t)3);

  if ((D & 3) == 0 && D4 >= 1 && D4 <= 128 && NC >= 1 && NC <= 256) {
    dim3 grid(B * NC), block(128);
    k_local<<<grid, block, 0, stream>>>(z, P, lengths, S, A, out, B, T, D4, NC);
    k_apply<<<grid, block, 0, stream>>>(z, P, S, A, lengths, out, B, T, D4, NC);
    return;
  }

  f_local<<<dim3(B * NC), dim3(128), 0, stream>>>(z, P, lengths, S, A, B, T, D, NC);
  f_carry<<<dim3(B * D4), dim3(NC), 0, stream>>>(S, A, Carry, D4, NC);
  f_apply<<<dim3(B * NC), dim3(128), 0, stream>>>(z, P, Carry, lengths, out, B, T, D, NC);
}